// Round 6
// baseline (146.305 us; speedup 1.0000x reference)
//
#include <hip/hip_runtime.h>
#include <hip/hip_bf16.h>
#include <stdint.h>

#define D_MODEL 1024
#define NHEADS  16
#define HDIM    64
#define BB      2
#define TT      2048
#define MROWS   (BB*TT)      // 4096
#define GK      1024         // reduction dim for all projections

typedef __bf16 bf16_8 __attribute__((ext_vector_type(8)));
typedef __bf16 bf16_4 __attribute__((ext_vector_type(4)));
typedef float  f32x4  __attribute__((ext_vector_type(4)));
typedef unsigned short u16;

__device__ __forceinline__ u16 f2bf(float f) {
    union { float f; uint32_t u; } c; c.f = f;
    uint32_t u = c.u;
    uint32_t r = (u + 0x7FFFu + ((u >> 16) & 1u)) >> 16;
    return (u16)r;
}
__device__ __forceinline__ uint32_t pk2bf(float a, float b) {
    return (uint32_t)f2bf(a) | ((uint32_t)f2bf(b) << 16);
}

__device__ __forceinline__ void gload16(const void* g, void* l) {
    __builtin_amdgcn_global_load_lds(
        (const __attribute__((address_space(1))) unsigned int*)g,
        (__attribute__((address_space(3))) unsigned int*)l,
        16, 0, 0);
}

// ---------------------------------------------------------------- convert
__global__ __launch_bounds__(256) void cvtk(
    const float* __restrict__ x,  const float* __restrict__ wq,
    const float* __restrict__ wk, const float* __restrict__ wv,
    const float* __restrict__ wo, const unsigned char* __restrict__ mk,
    u16* __restrict__ xb,  u16* __restrict__ wqb, u16* __restrict__ wkb,
    u16* __restrict__ wvb, u16* __restrict__ wob, uint32_t* __restrict__ pmb)
{
    int z = blockIdx.y;
    if (z == 5) {   // pack padding mask bits: pmb[b*64 + i], bit j = mask[b][32i+j]
        int gi = blockIdx.x*256 + threadIdx.x;
        if (gi < BB*TT/32) {
            uint32_t wv = 0;
            #pragma unroll
            for (int j = 0; j < 32; ++j)
                wv |= (mk[gi*32 + j] ? 1u : 0u) << j;
            pmb[gi] = wv;
        }
        return;
    }
    const float* in; u16* out; int n4;
    switch (z) {
        case 0: in = x;  out = xb;  n4 = MROWS*D_MODEL/4; break;
        case 1: in = wq; out = wqb; n4 = D_MODEL*D_MODEL/4; break;
        case 2: in = wk; out = wkb; n4 = D_MODEL*D_MODEL/4; break;
        case 3: in = wv; out = wvb; n4 = D_MODEL*D_MODEL/4; break;
        default: in = wo; out = wob; n4 = D_MODEL*D_MODEL/4; break;
    }
    for (int i = blockIdx.x*256 + threadIdx.x; i < n4; i += 1024*256) {
        float4 v = ((const float4*)in)[i];
        uint2 pk;
        pk.x = pk2bf(v.x, v.y);
        pk.y = pk2bf(v.z, v.w);
        ((uint2*)out)[i] = pk;
    }
}

// ---------------------------------------------------------------- GEMM body
// C(128x128) tile of A(4096x1024) * B(1024x1024)^T, both bf16 row-major.
// MODE 0: scatter bf16 into (B,H,T,D)   [Q (scaled), K]
// MODE 1: swapped-operand MFMA; store bf16 into (B,H,D,T) coalesced  [V^T]
// MODE 2: f32 row-major (4096x1024)     [final out]
// All modes: raw-barrier pipelined double-buffer (stage t+1 issued before
// compute t; single vmcnt(0)+s_barrier per K-step).
template<int MODE>
__device__ __forceinline__ void gemm_body(
    const u16* __restrict__ A, const u16* __restrict__ Bm,
    void* __restrict__ dst, float oscale)
{
    __shared__ u16 As[2][128*64];
    __shared__ u16 Bs[2][128*64];
    const int tid  = threadIdx.x;
    const int lane = tid & 63, w = tid >> 6;
    const int wr = w >> 1, wc = w & 1;
    const int g = lane >> 4, lr = lane & 15;
    const int bn = blockIdx.x & 7, bm = blockIdx.x >> 3;
    const int m0 = bm * 128, n0 = bn * 128;

    f32x4 acc[4][4];
    #pragma unroll
    for (int i = 0; i < 4; ++i)
        #pragma unroll
        for (int j = 0; j < 4; ++j)
            acc[i][j] = f32x4{0.f, 0.f, 0.f, 0.f};

    auto STG = [&](int kt, int buf) {
        int k0 = kt*64;
        #pragma unroll
        for (int r = 0; r < 4; ++r) {
            int o   = r*256 + tid;
            int row = o >> 3;
            int lc  = (o & 7) ^ (row & 7);
            gload16(A  + (size_t)(m0+row)*GK + k0 + lc*8,
                    (char*)&As[buf][0] + (size_t)(r*256 + w*64)*16);
            gload16(Bm + (size_t)(n0+row)*GK + k0 + lc*8,
                    (char*)&Bs[buf][0] + (size_t)(r*256 + w*64)*16);
        }
    };
    auto CMP = [&](const u16* Asc, const u16* Bsc) {
        #pragma unroll
        for (int ks = 0; ks < 2; ++ks) {
            bf16_8 af[4], bfr[4];
            #pragma unroll
            for (int mt = 0; mt < 4; ++mt) {
                int row = wr*64 + mt*16 + lr;
                int ch  = (ks*4 + g) ^ (row & 7);
                af[mt] = *(const bf16_8*)((const char*)Asc + row*128 + ch*16);
            }
            #pragma unroll
            for (int nt = 0; nt < 4; ++nt) {
                int row = wc*64 + nt*16 + lr;
                int ch  = (ks*4 + g) ^ (row & 7);
                bfr[nt] = *(const bf16_8*)((const char*)Bsc + row*128 + ch*16);
            }
            #pragma unroll
            for (int mt = 0; mt < 4; ++mt)
                #pragma unroll
                for (int nt = 0; nt < 4; ++nt) {
                    if (MODE == 1)
                        acc[mt][nt] = __builtin_amdgcn_mfma_f32_16x16x32_bf16(
                            bfr[nt], af[mt], acc[mt][nt], 0, 0, 0);
                    else
                        acc[mt][nt] = __builtin_amdgcn_mfma_f32_16x16x32_bf16(
                            af[mt], bfr[nt], acc[mt][nt], 0, 0, 0);
                }
        }
    };

    STG(0, 0);
    for (int kt = 0; kt < 16; ++kt) {
        asm volatile("s_waitcnt vmcnt(0)" ::: "memory");
        __builtin_amdgcn_s_barrier();
        if (kt + 1 < 16) STG(kt+1, (kt+1) & 1);
        __builtin_amdgcn_s_setprio(1);
        CMP(&As[kt & 1][0], &Bs[kt & 1][0]);
        __builtin_amdgcn_s_setprio(0);
    }

    #pragma unroll
    for (int mt = 0; mt < 4; ++mt) {
        #pragma unroll
        for (int nt = 0; nt < 4; ++nt) {
            #pragma unroll
            for (int r = 0; r < 4; ++r) {
                float v = acc[mt][nt][r];
                if (MODE == 2) {
                    int row = m0 + wr*64 + mt*16 + g*4 + r;
                    int col = n0 + wc*64 + nt*16 + lr;
                    ((float*)dst)[(size_t)row*D_MODEL + col] = v;
                } else if (MODE == 0) {
                    int row = m0 + wr*64 + mt*16 + g*4 + r;   // m: (b,t)
                    int col = n0 + wc*64 + nt*16 + lr;        // n: (h,d)
                    int b = row >> 11, t = row & (TT-1);
                    int h = col >> 6,  d = col & 63;
                    ((u16*)dst)[(((size_t)(b*NHEADS + h)*TT + t)*HDIM + d)] = f2bf(v*oscale);
                } else {  // MODE 1: acc row = n-side (h,d), col = m-side (b,t)
                    int nrow = n0 + wc*64 + nt*16 + g*4 + r;  // n: (h,d)
                    int mcol = m0 + wr*64 + mt*16 + lr;       // m: (b,t)
                    int h = nrow >> 6,  d = nrow & 63;
                    int b = mcol >> 11, t = mcol & (TT-1);
                    ((u16*)dst)[(((size_t)(b*NHEADS + h)*HDIM + d)*TT + t)] = f2bf(v);
                }
            }
        }
    }
}

__global__ __launch_bounds__(256) void gemm_qkv(
    const u16* __restrict__ xb,
    const u16* __restrict__ wqb, const u16* __restrict__ wkb, const u16* __restrict__ wvb,
    u16* __restrict__ Qb, u16* __restrict__ Kb, u16* __restrict__ VTb)
{
    int z = blockIdx.y;
    if (z == 0)      gemm_body<0>(xb, wqb, Qb, 0.18033688f);  // (1/8)*log2(e)
    else if (z == 1) gemm_body<0>(xb, wkb, Kb, 1.0f);
    else             gemm_body<1>(xb, wvb, VTb, 1.0f);
}

__global__ __launch_bounds__(256) void gemm_out(
    const u16* __restrict__ AOb, const u16* __restrict__ wob, float* __restrict__ out)
{
    gemm_body<2>(AOb, wob, out, 1.0f);
}

// ---------------------------------------------------------------- attention
// grid (8, 32) = 256 blocks (1/CU), 512 threads = 8 waves.
// Block owns complementary q-tile pair {qtH = 15-p, qtL = p} -> constant work.
// Wave owns 16 heavy rows + 16 light rows (light reversed: per-wave 33 units).
// bh = 4*blockIdx.x + (y&3): all 8 blocks of a bh land on one XCD (L2 reuse).
// KVBLK=64, 3 LDS buffers, depth-2 prefetch, counted vmcnt(2).
__global__ __launch_bounds__(512, 2) void attn_fwd(
    const u16* __restrict__ Qb, const u16* __restrict__ Kb,
    const u16* __restrict__ VTb, const uint32_t* __restrict__ pmb,
    u16* __restrict__ AO)
{
    __shared__ u16 Ks[3][64*64];      // 24 KB
    __shared__ u16 Vs[3][64*64];      // 24 KB
    __shared__ u16 Pl[8][2304];       // 36 KB per-wave P / epilogue transpose
    __shared__ uint32_t Ml[64];       // mask bits for this batch

    const int tid = threadIdx.x, lane = tid & 63, w = tid >> 6;
    const int g = lane >> 4, lr = lane & 15;
    const int x = blockIdx.x, y = blockIdx.y;
    const int bh = x*4 + (y & 3), p = y >> 2;
    const int b = bh >> 4, h = bh & 15;
    const int qtH = 15 - p, qtL = p;
    const int qlo0 = qtH*128 + w*16;            // heavy rows
    const int qlo1 = qtL*128 + (7-w)*16;        // light rows (reversed)
    const int ta0  = (qlo0 + 15) >> 6;          // last kv tile for heavy
    const int ta1  = (qlo1 + 15) >> 6;          // last kv tile for light
    const int nt   = 2*qtH + 2;

    const u16* Qh = Qb  + (size_t)bh*TT*HDIM;
    const u16* Kh = Kb  + (size_t)bh*TT*HDIM;
    const u16* Vh = VTb + (size_t)bh*HDIM*TT;
    char* Pw = (char*)&Pl[w][0];

    if (tid < 64) Ml[tid] = pmb[b*(TT/32) + tid];

    // Q B-frags (pre-scaled by log2e/8): qf[qg][dc] = Q[qlo+lr][dc*32+g*8..]
    bf16_8 qf[2][2];
    #pragma unroll
    for (int dc = 0; dc < 2; ++dc) {
        qf[0][dc] = *(const bf16_8*)(Qh + (size_t)(qlo0+lr)*HDIM + dc*32 + g*8);
        qf[1][dc] = *(const bf16_8*)(Qh + (size_t)(qlo1+lr)*HDIM + dc*32 + g*8);
    }

    f32x4 o[2][4];                    // O^T: o[qg][dt][r] = O[dt*16+4g+r][q=qlo+lr]
    #pragma unroll
    for (int qg = 0; qg < 2; ++qg)
        #pragma unroll
        for (int i = 0; i < 4; ++i) o[qg][i] = f32x4{0.f, 0.f, 0.f, 0.f};
    float m_run[2] = {-1e30f, -1e30f}, l_run[2] = {0.f, 0.f};

    auto STAGE = [&](int t, int buf) {
        int kv0 = t*64;
        int row = tid >> 3;                        // 0..63
        int lc  = (tid & 7) ^ (row & 7);
        char* lk = (char*)&Ks[buf][0] + (size_t)(w*64)*16;   // wave-uniform base
        char* lv = (char*)&Vs[buf][0] + (size_t)(w*64)*16;
        gload16(Kh + (size_t)(kv0+row)*HDIM + lc*8, lk);
        gload16(Vh + (size_t)row*TT + kv0 + lc*8, lv);
    };

    STAGE(0, 0);          // nt >= 2 always
    STAGE(1, 1);

    int cur = 0;
    for (int t = 0; t < nt; ++t) {
        if (t + 1 < nt) asm volatile("s_waitcnt vmcnt(2) lgkmcnt(0)" ::: "memory");
        else            asm volatile("s_waitcnt vmcnt(0) lgkmcnt(0)" ::: "memory");
        __builtin_amdgcn_s_barrier();
        if (t + 2 < nt) { int nb = cur + 2; if (nb >= 3) nb -= 3; STAGE(t+2, nb); }

        const bool a0 = (t <= ta0), a1 = (t <= ta1);
        if (a0 || a1) {
            const int kv0 = t*64;
            const u16* Kc = &Ks[cur][0];
            const u16* Vc = &Vs[cur][0];

            // ---- QK^T swapped: s[qg][kvb] lane: q=qlo+lr, kv=kv0+16kvb+4g+reg
            f32x4 s[2][4];
            __builtin_amdgcn_s_setprio(1);
            #pragma unroll
            for (int kvb = 0; kvb < 4; ++kvb) {
                int row = kvb*16 + lr;
                int sw  = row & 7;
                bf16_8 k0 = *(const bf16_8*)(Kc + row*64 + ((g    ) ^ sw)*8);
                bf16_8 k1 = *(const bf16_8*)(Kc + row*64 + ((4 + g) ^ sw)*8);
                if (a0) {
                    f32x4 z = f32x4{0.f, 0.f, 0.f, 0.f};
                    z = __builtin_amdgcn_mfma_f32_16x16x32_bf16(k0, qf[0][0], z, 0, 0, 0);
                    z = __builtin_amdgcn_mfma_f32_16x16x32_bf16(k1, qf[0][1], z, 0, 0, 0);
                    s[0][kvb] = z;
                }
                if (a1) {
                    f32x4 z = f32x4{0.f, 0.f, 0.f, 0.f};
                    z = __builtin_amdgcn_mfma_f32_16x16x32_bf16(k0, qf[1][0], z, 0, 0, 0);
                    z = __builtin_amdgcn_mfma_f32_16x16x32_bf16(k1, qf[1][1], z, 0, 0, 0);
                    s[1][kvb] = z;
                }
            }
            __builtin_amdgcn_s_setprio(0);

            // ---- V^T A-frags (LDS; latency hides under softmax)
            bf16_8 vf[4][2];
            #pragma unroll
            for (int dt = 0; dt < 4; ++dt)
                #pragma unroll
                for (int hh = 0; hh < 2; ++hh)
                    vf[dt][hh] = *(const bf16_8*)(Vc + (dt*16+lr)*64 + ((hh*4+g) ^ (lr&7))*8);

            uint64_t m64 = (uint64_t)Ml[2*t] | ((uint64_t)Ml[2*t+1] << 32);

            // ---- per-qg: mask, online softmax (exp2, defer-max THR=8), P write
            #pragma unroll
            for (int qg = 0; qg < 2; ++qg) {
                if (!(qg == 0 ? a0 : a1)) continue;
                const int qlo = qg ? qlo1 : qlo0;
                const int ta  = qg ? ta1  : ta0;
                if (m64) {
                    #pragma unroll
                    for (int kvb = 0; kvb < 4; ++kvb) {
                        uint32_t nib = (uint32_t)(m64 >> (kvb*16 + 4*g)) & 0xFu;
                        #pragma unroll
                        for (int r = 0; r < 4; ++r)
                            if ((nib >> r) & 1) s[qg][kvb][r] = -1e30f;
                    }
                }
                if (t == ta) {
                    int q = qlo + lr;
                    #pragma unroll
                    for (int kvb = 0; kvb < 4; ++kvb) {
                        int kvb0 = kv0 + kvb*16 + 4*g;
                        #pragma unroll
                        for (int r = 0; r < 4; ++r)
                            if (kvb0 + r > q) s[qg][kvb][r] = -1e30f;
                    }
                }
                float t0 = fmaxf(fmaxf(s[qg][0][0], s[qg][0][1]), fmaxf(s[qg][0][2], s[qg][0][3]));
                float t1 = fmaxf(fmaxf(s[qg][1][0], s[qg][1][1]), fmaxf(s[qg][1][2], s[qg][1][3]));
                float t2 = fmaxf(fmaxf(s[qg][2][0], s[qg][2][1]), fmaxf(s[qg][2][2], s[qg][2][3]));
                float t3 = fmaxf(fmaxf(s[qg][3][0], s[qg][3][1]), fmaxf(s[qg][3][2], s[qg][3][3]));
                float mx = fmaxf(fmaxf(t0, t1), fmaxf(t2, t3));
                mx = fmaxf(mx, __shfl_xor(mx, 16));
                mx = fmaxf(mx, __shfl_xor(mx, 32));
                if (__any(mx > m_run[qg] + 8.f)) {
                    float nm = fmaxf(m_run[qg], mx);
                    float fs = __builtin_amdgcn_exp2f(m_run[qg] - nm);
                    #pragma unroll
                    for (int dt = 0; dt < 4; ++dt)
                        #pragma unroll
                        for (int r = 0; r < 4; ++r)
                            o[qg][dt][r] *= fs;
                    l_run[qg] *= fs;
                    m_run[qg] = nm;
                }
                #pragma unroll
                for (int kvb = 0; kvb < 4; ++kvb)
                    #pragma unroll
                    for (int r = 0; r < 4; ++r)
                        s[qg][kvb][r] = __builtin_amdgcn_exp2f(s[qg][kvb][r] - m_run[qg]);
                float p0 = (s[qg][0][0] + s[qg][0][1]) + (s[qg][0][2] + s[qg][0][3]);
                float p1 = (s[qg][1][0] + s[qg][1][1]) + (s[qg][1][2] + s[qg][1][3]);
                float p2 = (s[qg][2][0] + s[qg][2][1]) + (s[qg][2][2] + s[qg][2][3]);
                float p3 = (s[qg][3][0] + s[qg][3][1]) + (s[qg][3][2] + s[qg][3][3]);
                float ps = (p0 + p1) + (p2 + p3);
                ps += __shfl_xor(ps, 16);
                ps += __shfl_xor(ps, 32);
                l_run[qg] += ps;
                #pragma unroll
                for (int kvb = 0; kvb < 4; ++kvb) {
                    bf16_4 pk;
                    pk[0] = (__bf16)s[qg][kvb][0]; pk[1] = (__bf16)s[qg][kvb][1];
                    pk[2] = (__bf16)s[qg][kvb][2]; pk[3] = (__bf16)s[qg][kvb][3];
                    *(bf16_4*)(Pw + qg*2304 + lr*144 + kvb*32 + g*8) = pk;
                }
            }
            asm volatile("s_waitcnt lgkmcnt(0)" ::: "memory");
            __builtin_amdgcn_sched_barrier(0);

            // ---- PV swapped: O^T += V^T(A) x P(B)
            __builtin_amdgcn_s_setprio(1);
            #pragma unroll
            for (int qg = 0; qg < 2; ++qg) {
                if (!(qg == 0 ? a0 : a1)) continue;
                #pragma unroll
                for (int hh = 0; hh < 2; ++hh) {
                    bf16_8 pa = *(const bf16_8*)(Pw + qg*2304 + lr*144 + hh*64 + g*16);
                    #pragma unroll
                    for (int dt = 0; dt < 4; ++dt)
                        o[qg][dt] = __builtin_amdgcn_mfma_f32_16x16x32_bf16(
                            vf[dt][hh], pa, o[qg][dt], 0, 0, 0);
                }
            }
            __builtin_amdgcn_s_setprio(0);
        }

        ++cur; if (cur == 3) cur = 0;
    }

    // ---- epilogue: per-lane divide, LDS transpose, coalesced 128B row stores
    #pragma unroll
    for (int qg = 0; qg < 2; ++qg) {
        float linv = (l_run[qg] > 0.f) ? 1.f/l_run[qg] : 0.f;
        u16* ot = (u16*)(Pw + qg*2304);            // [d 64][q 16] stride 17
        #pragma unroll
        for (int dt = 0; dt < 4; ++dt)
            #pragma unroll
            for (int r = 0; r < 4; ++r)
                ot[(dt*16 + 4*g + r)*17 + lr] = f2bf(o[qg][dt][r]*linv);
    }
    asm volatile("s_waitcnt lgkmcnt(0)" ::: "memory");
    __builtin_amdgcn_sched_barrier(0);
    #pragma unroll
    for (int qg = 0; qg < 2; ++qg) {
        const int qlo = qg ? qlo1 : qlo0;
        const u16* ot = (const u16*)(Pw + qg*2304);
        #pragma unroll
        for (int qq = 0; qq < 16; ++qq)
            AO[((size_t)(b*TT + qlo + qq))*D_MODEL + h*HDIM + lane] = ot[lane*17 + qq];
    }
}

// ---------------------------------------------------------------- launch
extern "C" void kernel_launch(void* const* d_in, const int* in_sizes, int n_in,
                              void* d_out, int out_size, void* d_ws, size_t ws_size,
                              hipStream_t stream)
{
    const float* x  = (const float*)d_in[0];
    const unsigned char* mask = (const unsigned char*)d_in[1];
    const float* Wq = (const float*)d_in[2];
    const float* Wk = (const float*)d_in[3];
    const float* Wv = (const float*)d_in[4];
    const float* Wo = (const float*)d_in[5];
    float* out = (float*)d_out;

    char* ws = (char*)d_ws;
    u16* xb  = (u16*)(ws + 0);          // 8 MB (reused as AO after QKV)
    u16* wqb = (u16*)(ws + 8388608);
    u16* wkb = (u16*)(ws + 10485760);
    u16* wvb = (u16*)(ws + 12582912);
    u16* wob = (u16*)(ws + 14680064);
    u16* Qb  = (u16*)(ws + 16777216);
    u16* Kb  = (u16*)(ws + 25165824);
    u16* VTb = (u16*)(ws + 33554432);
    uint32_t* pmb = (uint32_t*)(ws + 41943040);   // 512 B mask bits
    u16* AOb = xb;

    cvtk<<<dim3(1024, 6), 256, 0, stream>>>(x, Wq, Wk, Wv, Wo, mask,
                                            xb, wqb, wkb, wvb, wob, pmb);
    gemm_qkv<<<dim3(256, 3), 256, 0, stream>>>(xb, wqb, wkb, wvb, Qb, Kb, VTb);
    attn_fwd<<<dim3(8, 32), 512, 0, stream>>>(Qb, Kb, VTb, pmb, AOb);
    gemm_out<<<dim3(256), 256, 0, stream>>>(AOb, wob, out);
}

// Round 7
// 126.959 us; speedup vs baseline: 1.1524x; 1.1524x over previous
//
#include <hip/hip_runtime.h>
#include <hip/hip_bf16.h>
#include <stdint.h>

#define D_MODEL 1024
#define NHEADS  16
#define HDIM    64
#define BB      2
#define TT      2048
#define MROWS   (BB*TT)      // 4096
#define GK      1024         // reduction dim for all projections

typedef __bf16 bf16_8 __attribute__((ext_vector_type(8)));
typedef __bf16 bf16_4 __attribute__((ext_vector_type(4)));
typedef float  f32x4  __attribute__((ext_vector_type(4)));
typedef unsigned short u16;

__device__ __forceinline__ u16 f2bf(float f) {
    union { float f; uint32_t u; } c; c.f = f;
    uint32_t u = c.u;
    uint32_t r = (u + 0x7FFFu + ((u >> 16) & 1u)) >> 16;
    return (u16)r;
}
__device__ __forceinline__ uint32_t pk2bf(float a, float b) {
    return (uint32_t)f2bf(a) | ((uint32_t)f2bf(b) << 16);
}

__device__ __forceinline__ void gload16(const void* g, void* l) {
    __builtin_amdgcn_global_load_lds(
        (const __attribute__((address_space(1))) unsigned int*)g,
        (__attribute__((address_space(3))) unsigned int*)l,
        16, 0, 0);
}

// ---------------------------------------------------------------- convert
__global__ __launch_bounds__(256) void cvtk(
    const float* __restrict__ x,  const float* __restrict__ wq,
    const float* __restrict__ wk, const float* __restrict__ wv,
    const float* __restrict__ wo, const unsigned char* __restrict__ mk,
    u16* __restrict__ xb,  u16* __restrict__ wqb, u16* __restrict__ wkb,
    u16* __restrict__ wvb, u16* __restrict__ wob, uint32_t* __restrict__ pmb)
{
    int z = blockIdx.y;
    if (z == 5) {   // pack padding mask bits: pmb[b*64 + i], bit j = mask[b][32i+j]
        int gi = blockIdx.x*256 + threadIdx.x;
        if (gi < BB*TT/32) {
            uint32_t wv = 0;
            #pragma unroll
            for (int j = 0; j < 32; ++j)
                wv |= (mk[gi*32 + j] ? 1u : 0u) << j;
            pmb[gi] = wv;
        }
        return;
    }
    const float* in; u16* out; int n4;
    switch (z) {
        case 0: in = x;  out = xb;  n4 = MROWS*D_MODEL/4; break;
        case 1: in = wq; out = wqb; n4 = D_MODEL*D_MODEL/4; break;
        case 2: in = wk; out = wkb; n4 = D_MODEL*D_MODEL/4; break;
        case 3: in = wv; out = wvb; n4 = D_MODEL*D_MODEL/4; break;
        default: in = wo; out = wob; n4 = D_MODEL*D_MODEL/4; break;
    }
    for (int i = blockIdx.x*256 + threadIdx.x; i < n4; i += 1024*256) {
        float4 v = ((const float4*)in)[i];
        uint2 pk;
        pk.x = pk2bf(v.x, v.y);
        pk.y = pk2bf(v.z, v.w);
        ((uint2*)out)[i] = pk;
    }
}

// ---------------------------------------------------------------- GEMM body
// C(128x128) tile of A(4096x1024) * B(1024x1024)^T, both bf16 row-major.
// MODE 0: scatter bf16 into (B,H,T,D)   [Q (scaled), K]
// MODE 1: swapped-operand MFMA; store bf16 into (B,H,D,T) coalesced  [V^T]
// MODE 2: f32 row-major (4096x1024)     [final out]
// NB=1: single-buffer, __syncthreads x2 (3 blocks/CU TLP -- for gemm_qkv).
// NB=2: raw-barrier pipelined double-buffer (1-block/CU launches -- gemm_out).
// blockIdx decode is XCD-aware: the 8 bn-blocks sharing one A-panel land on
// the same XCD (dispatch round-robins linear id % 8).
template<int MODE, int NB>
__device__ __forceinline__ void gemm_body(
    const u16* __restrict__ A, const u16* __restrict__ Bm,
    void* __restrict__ dst, float oscale)
{
    __shared__ u16 As[NB][128*64];
    __shared__ u16 Bs[NB][128*64];
    const int tid  = threadIdx.x;
    const int lane = tid & 63, w = tid >> 6;
    const int wr = w >> 1, wc = w & 1;
    const int g = lane >> 4, lr = lane & 15;
    // XCD-aware: x = xcd + 8*(bn + 8*bmh); bm = bmh*8 + xcd
    const int xcd = blockIdx.x & 7, qq_ = blockIdx.x >> 3;
    const int bn = qq_ & 7, bm = (qq_ >> 3)*8 + xcd;
    const int m0 = bm * 128, n0 = bn * 128;

    f32x4 acc[4][4];
    #pragma unroll
    for (int i = 0; i < 4; ++i)
        #pragma unroll
        for (int j = 0; j < 4; ++j)
            acc[i][j] = f32x4{0.f, 0.f, 0.f, 0.f};

    auto STG = [&](int kt, int buf) {
        int k0 = kt*64;
        #pragma unroll
        for (int r = 0; r < 4; ++r) {
            int o   = r*256 + tid;
            int row = o >> 3;
            int lc  = (o & 7) ^ (row & 7);
            gload16(A  + (size_t)(m0+row)*GK + k0 + lc*8,
                    (char*)&As[buf][0] + (size_t)(r*256 + w*64)*16);
            gload16(Bm + (size_t)(n0+row)*GK + k0 + lc*8,
                    (char*)&Bs[buf][0] + (size_t)(r*256 + w*64)*16);
        }
    };
    auto CMP = [&](const u16* Asc, const u16* Bsc) {
        #pragma unroll
        for (int ks = 0; ks < 2; ++ks) {
            bf16_8 af[4], bfr[4];
            #pragma unroll
            for (int mt = 0; mt < 4; ++mt) {
                int row = wr*64 + mt*16 + lr;
                int ch  = (ks*4 + g) ^ (row & 7);
                af[mt] = *(const bf16_8*)((const char*)Asc + row*128 + ch*16);
            }
            #pragma unroll
            for (int nt = 0; nt < 4; ++nt) {
                int row = wc*64 + nt*16 + lr;
                int ch  = (ks*4 + g) ^ (row & 7);
                bfr[nt] = *(const bf16_8*)((const char*)Bsc + row*128 + ch*16);
            }
            #pragma unroll
            for (int mt = 0; mt < 4; ++mt)
                #pragma unroll
                for (int nt = 0; nt < 4; ++nt) {
                    if (MODE == 1)
                        acc[mt][nt] = __builtin_amdgcn_mfma_f32_16x16x32_bf16(
                            bfr[nt], af[mt], acc[mt][nt], 0, 0, 0);
                    else
                        acc[mt][nt] = __builtin_amdgcn_mfma_f32_16x16x32_bf16(
                            af[mt], bfr[nt], acc[mt][nt], 0, 0, 0);
                }
        }
    };

    if (NB == 2) {
        STG(0, 0);
        for (int kt = 0; kt < 16; ++kt) {
            asm volatile("s_waitcnt vmcnt(0)" ::: "memory");
            __builtin_amdgcn_s_barrier();
            if (kt + 1 < 16) STG(kt+1, (kt+1) & 1);
            __builtin_amdgcn_s_setprio(1);
            CMP(&As[kt & 1][0], &Bs[kt & 1][0]);
            __builtin_amdgcn_s_setprio(0);
        }
    } else {
        for (int kt = 0; kt < 16; ++kt) {
            STG(kt, 0);
            __syncthreads();
            CMP(&As[0][0], &Bs[0][0]);
            __syncthreads();
        }
    }

    #pragma unroll
    for (int mt = 0; mt < 4; ++mt) {
        #pragma unroll
        for (int nt = 0; nt < 4; ++nt) {
            #pragma unroll
            for (int r = 0; r < 4; ++r) {
                float v = acc[mt][nt][r];
                if (MODE == 2) {
                    int row = m0 + wr*64 + mt*16 + g*4 + r;
                    int col = n0 + wc*64 + nt*16 + lr;
                    ((float*)dst)[(size_t)row*D_MODEL + col] = v;
                } else if (MODE == 0) {
                    int row = m0 + wr*64 + mt*16 + g*4 + r;   // m: (b,t)
                    int col = n0 + wc*64 + nt*16 + lr;        // n: (h,d)
                    int b = row >> 11, t = row & (TT-1);
                    int h = col >> 6,  d = col & 63;
                    ((u16*)dst)[(((size_t)(b*NHEADS + h)*TT + t)*HDIM + d)] = f2bf(v*oscale);
                } else {  // MODE 1: acc row = n-side (h,d), col = m-side (b,t)
                    int nrow = n0 + wc*64 + nt*16 + g*4 + r;  // n: (h,d)
                    int mcol = m0 + wr*64 + mt*16 + lr;       // m: (b,t)
                    int h = nrow >> 6,  d = nrow & 63;
                    int b = mcol >> 11, t = mcol & (TT-1);
                    ((u16*)dst)[(((size_t)(b*NHEADS + h)*HDIM + d)*TT + t)] = f2bf(v);
                }
            }
        }
    }
}

__global__ __launch_bounds__(256) void gemm_qkv(
    const u16* __restrict__ xb,
    const u16* __restrict__ wqb, const u16* __restrict__ wkb, const u16* __restrict__ wvb,
    u16* __restrict__ Qb, u16* __restrict__ Kb, u16* __restrict__ VTb)
{
    int z = blockIdx.y;
    if (z == 0)      gemm_body<0,1>(xb, wqb, Qb, 0.18033688f);  // (1/8)*log2(e)
    else if (z == 1) gemm_body<0,1>(xb, wkb, Kb, 1.0f);
    else             gemm_body<1,1>(xb, wvb, VTb, 1.0f);
}

__global__ __launch_bounds__(256) void gemm_out(
    const u16* __restrict__ AOb, const u16* __restrict__ wob, float* __restrict__ out)
{
    gemm_body<2,2>(AOb, wob, out, 1.0f);
}

// ---------------------------------------------------------------- attention
// grid (8, 32) = 256 blocks (1/CU), 512 threads = 8 waves.
// Block owns complementary q-tile pair {qtH = 15-p, qtL = p} -> constant work.
// Wave owns 16 heavy rows + 16 light rows (light reversed: per-wave 33 units).
// bh = 4*blockIdx.x + (y&3): all 8 blocks of a bh land on one XCD (L2 reuse).
// KVBLK=64, 3 LDS buffers, depth-2 prefetch, counted vmcnt(2).
__global__ __launch_bounds__(512, 2) void attn_fwd(
    const u16* __restrict__ Qb, const u16* __restrict__ Kb,
    const u16* __restrict__ VTb, const uint32_t* __restrict__ pmb,
    u16* __restrict__ AO)
{
    __shared__ u16 Ks[3][64*64];      // 24 KB
    __shared__ u16 Vs[3][64*64];      // 24 KB
    __shared__ u16 Pl[8][2304];       // 36 KB per-wave P / epilogue transpose
    __shared__ uint32_t Ml[64];       // mask bits for this batch

    const int tid = threadIdx.x, lane = tid & 63, w = tid >> 6;
    const int g = lane >> 4, lr = lane & 15;
    const int x = blockIdx.x, y = blockIdx.y;
    const int bh = x*4 + (y & 3), p = y >> 2;
    const int b = bh >> 4, h = bh & 15;
    const int qtH = 15 - p, qtL = p;
    const int qlo0 = qtH*128 + w*16;            // heavy rows
    const int qlo1 = qtL*128 + (7-w)*16;        // light rows (reversed)
    const int ta0  = (qlo0 + 15) >> 6;          // last kv tile for heavy
    const int ta1  = (qlo1 + 15) >> 6;          // last kv tile for light
    const int nt   = 2*qtH + 2;

    const u16* Qh = Qb  + (size_t)bh*TT*HDIM;
    const u16* Kh = Kb  + (size_t)bh*TT*HDIM;
    const u16* Vh = VTb + (size_t)bh*HDIM*TT;
    char* Pw = (char*)&Pl[w][0];

    if (tid < 64) Ml[tid] = pmb[b*(TT/32) + tid];

    // Q B-frags (pre-scaled by log2e/8): qf[qg][dc] = Q[qlo+lr][dc*32+g*8..]
    bf16_8 qf[2][2];
    #pragma unroll
    for (int dc = 0; dc < 2; ++dc) {
        qf[0][dc] = *(const bf16_8*)(Qh + (size_t)(qlo0+lr)*HDIM + dc*32 + g*8);
        qf[1][dc] = *(const bf16_8*)(Qh + (size_t)(qlo1+lr)*HDIM + dc*32 + g*8);
    }

    f32x4 o[2][4];                    // O^T: o[qg][dt][r] = O[dt*16+4g+r][q=qlo+lr]
    #pragma unroll
    for (int qg = 0; qg < 2; ++qg)
        #pragma unroll
        for (int i = 0; i < 4; ++i) o[qg][i] = f32x4{0.f, 0.f, 0.f, 0.f};
    float m_run[2] = {-1e30f, -1e30f}, l_run[2] = {0.f, 0.f};

    auto STAGE = [&](int t, int buf) {
        int kv0 = t*64;
        int row = tid >> 3;                        // 0..63
        int lc  = (tid & 7) ^ (row & 7);
        char* lk = (char*)&Ks[buf][0] + (size_t)(w*64)*16;   // wave-uniform base
        char* lv = (char*)&Vs[buf][0] + (size_t)(w*64)*16;
        gload16(Kh + (size_t)(kv0+row)*HDIM + lc*8, lk);
        gload16(Vh + (size_t)row*TT + kv0 + lc*8, lv);
    };

    STAGE(0, 0);          // nt >= 2 always
    STAGE(1, 1);

    int cur = 0;
    for (int t = 0; t < nt; ++t) {
        if (t + 1 < nt) asm volatile("s_waitcnt vmcnt(2) lgkmcnt(0)" ::: "memory");
        else            asm volatile("s_waitcnt vmcnt(0) lgkmcnt(0)" ::: "memory");
        __builtin_amdgcn_s_barrier();
        if (t + 2 < nt) { int nb = cur + 2; if (nb >= 3) nb -= 3; STAGE(t+2, nb); }

        const bool a0 = (t <= ta0), a1 = (t <= ta1);
        if (a0 || a1) {
            const int kv0 = t*64;
            const u16* Kc = &Ks[cur][0];
            const u16* Vc = &Vs[cur][0];

            // ---- QK^T swapped: s[qg][kvb] lane: q=qlo+lr, kv=kv0+16kvb+4g+reg
            f32x4 s[2][4];
            __builtin_amdgcn_s_setprio(1);
            #pragma unroll
            for (int kvb = 0; kvb < 4; ++kvb) {
                int row = kvb*16 + lr;
                int sw  = row & 7;
                bf16_8 k0 = *(const bf16_8*)(Kc + row*64 + ((g    ) ^ sw)*8);
                bf16_8 k1 = *(const bf16_8*)(Kc + row*64 + ((4 + g) ^ sw)*8);
                if (a0) {
                    f32x4 z = f32x4{0.f, 0.f, 0.f, 0.f};
                    z = __builtin_amdgcn_mfma_f32_16x16x32_bf16(k0, qf[0][0], z, 0, 0, 0);
                    z = __builtin_amdgcn_mfma_f32_16x16x32_bf16(k1, qf[0][1], z, 0, 0, 0);
                    s[0][kvb] = z;
                }
                if (a1) {
                    f32x4 z = f32x4{0.f, 0.f, 0.f, 0.f};
                    z = __builtin_amdgcn_mfma_f32_16x16x32_bf16(k0, qf[1][0], z, 0, 0, 0);
                    z = __builtin_amdgcn_mfma_f32_16x16x32_bf16(k1, qf[1][1], z, 0, 0, 0);
                    s[1][kvb] = z;
                }
            }
            __builtin_amdgcn_s_setprio(0);

            // ---- V^T A-frags (LDS; latency hides under softmax)
            bf16_8 vf[4][2];
            #pragma unroll
            for (int dt = 0; dt < 4; ++dt)
                #pragma unroll
                for (int hh = 0; hh < 2; ++hh)
                    vf[dt][hh] = *(const bf16_8*)(Vc + (dt*16+lr)*64 + ((hh*4+g) ^ (lr&7))*8);

            uint64_t m64 = (uint64_t)Ml[2*t] | ((uint64_t)Ml[2*t+1] << 32);

            // ---- per-qg: mask, online softmax (exp2, defer-max THR=8), P write
            #pragma unroll
            for (int qg = 0; qg < 2; ++qg) {
                if (!(qg == 0 ? a0 : a1)) continue;
                const int qlo = qg ? qlo1 : qlo0;
                const int ta  = qg ? ta1  : ta0;
                if (m64) {
                    #pragma unroll
                    for (int kvb = 0; kvb < 4; ++kvb) {
                        uint32_t nib = (uint32_t)(m64 >> (kvb*16 + 4*g)) & 0xFu;
                        #pragma unroll
                        for (int r = 0; r < 4; ++r)
                            if ((nib >> r) & 1) s[qg][kvb][r] = -1e30f;
                    }
                }
                if (t == ta) {
                    int q = qlo + lr;
                    #pragma unroll
                    for (int kvb = 0; kvb < 4; ++kvb) {
                        int kvb0 = kv0 + kvb*16 + 4*g;
                        #pragma unroll
                        for (int r = 0; r < 4; ++r)
                            if (kvb0 + r > q) s[qg][kvb][r] = -1e30f;
                    }
                }
                float t0 = fmaxf(fmaxf(s[qg][0][0], s[qg][0][1]), fmaxf(s[qg][0][2], s[qg][0][3]));
                float t1 = fmaxf(fmaxf(s[qg][1][0], s[qg][1][1]), fmaxf(s[qg][1][2], s[qg][1][3]));
                float t2 = fmaxf(fmaxf(s[qg][2][0], s[qg][2][1]), fmaxf(s[qg][2][2], s[qg][2][3]));
                float t3 = fmaxf(fmaxf(s[qg][3][0], s[qg][3][1]), fmaxf(s[qg][3][2], s[qg][3][3]));
                float mx = fmaxf(fmaxf(t0, t1), fmaxf(t2, t3));
                mx = fmaxf(mx, __shfl_xor(mx, 16));
                mx = fmaxf(mx, __shfl_xor(mx, 32));
                if (__any(mx > m_run[qg] + 8.f)) {
                    float nm = fmaxf(m_run[qg], mx);
                    float fs = __builtin_amdgcn_exp2f(m_run[qg] - nm);
                    #pragma unroll
                    for (int dt = 0; dt < 4; ++dt)
                        #pragma unroll
                        for (int r = 0; r < 4; ++r)
                            o[qg][dt][r] *= fs;
                    l_run[qg] *= fs;
                    m_run[qg] = nm;
                }
                #pragma unroll
                for (int kvb = 0; kvb < 4; ++kvb)
                    #pragma unroll
                    for (int r = 0; r < 4; ++r)
                        s[qg][kvb][r] = __builtin_amdgcn_exp2f(s[qg][kvb][r] - m_run[qg]);
                float p0 = (s[qg][0][0] + s[qg][0][1]) + (s[qg][0][2] + s[qg][0][3]);
                float p1 = (s[qg][1][0] + s[qg][1][1]) + (s[qg][1][2] + s[qg][1][3]);
                float p2 = (s[qg][2][0] + s[qg][2][1]) + (s[qg][2][2] + s[qg][2][3]);
                float p3 = (s[qg][3][0] + s[qg][3][1]) + (s[qg][3][2] + s[qg][3][3]);
                float ps = (p0 + p1) + (p2 + p3);
                ps += __shfl_xor(ps, 16);
                ps += __shfl_xor(ps, 32);
                l_run[qg] += ps;
                #pragma unroll
                for (int kvb = 0; kvb < 4; ++kvb) {
                    bf16_4 pk;
                    pk[0] = (__bf16)s[qg][kvb][0]; pk[1] = (__bf16)s[qg][kvb][1];
                    pk[2] = (__bf16)s[qg][kvb][2]; pk[3] = (__bf16)s[qg][kvb][3];
                    *(bf16_4*)(Pw + qg*2304 + lr*144 + kvb*32 + g*8) = pk;
                }
            }
            asm volatile("s_waitcnt lgkmcnt(0)" ::: "memory");
            __builtin_amdgcn_sched_barrier(0);

            // ---- PV swapped: O^T += V^T(A) x P(B)
            __builtin_amdgcn_s_setprio(1);
            #pragma unroll
            for (int qg = 0; qg < 2; ++qg) {
                if (!(qg == 0 ? a0 : a1)) continue;
                #pragma unroll
                for (int hh = 0; hh < 2; ++hh) {
                    bf16_8 pa = *(const bf16_8*)(Pw + qg*2304 + lr*144 + hh*64 + g*16);
                    #pragma unroll
                    for (int dt = 0; dt < 4; ++dt)
                        o[qg][dt] = __builtin_amdgcn_mfma_f32_16x16x32_bf16(
                            vf[dt][hh], pa, o[qg][dt], 0, 0, 0);
                }
            }
            __builtin_amdgcn_s_setprio(0);
        }

        ++cur; if (cur == 3) cur = 0;
    }

    // ---- epilogue: per-lane divide, LDS transpose, coalesced 128B row stores
    #pragma unroll
    for (int qg = 0; qg < 2; ++qg) {
        float linv = (l_run[qg] > 0.f) ? 1.f/l_run[qg] : 0.f;
        u16* ot = (u16*)(Pw + qg*2304);            // [d 64][q 16] stride 17
        #pragma unroll
        for (int dt = 0; dt < 4; ++dt)
            #pragma unroll
            for (int r = 0; r < 4; ++r)
                ot[(dt*16 + 4*g + r)*17 + lr] = f2bf(o[qg][dt][r]*linv);
    }
    asm volatile("s_waitcnt lgkmcnt(0)" ::: "memory");
    __builtin_amdgcn_sched_barrier(0);
    #pragma unroll
    for (int qg = 0; qg < 2; ++qg) {
        const int qlo = qg ? qlo1 : qlo0;
        const u16* ot = (const u16*)(Pw + qg*2304);
        #pragma unroll
        for (int qq = 0; qq < 16; ++qq)
            AO[((size_t)(b*TT + qlo + qq))*D_MODEL + h*HDIM + lane] = ot[lane*17 + qq];
    }
}

// ---------------------------------------------------------------- launch
extern "C" void kernel_launch(void* const* d_in, const int* in_sizes, int n_in,
                              void* d_out, int out_size, void* d_ws, size_t ws_size,
                              hipStream_t stream)
{
    const float* x  = (const float*)d_in[0];
    const unsigned char* mask = (const unsigned char*)d_in[1];
    const float* Wq = (const float*)d_in[2];
    const float* Wk = (const float*)d_in[3];
    const float* Wv = (const float*)d_in[4];
    const float* Wo = (const float*)d_in[5];
    float* out = (float*)d_out;

    char* ws = (char*)d_ws;
    u16* xb  = (u16*)(ws + 0);          // 8 MB (reused as AO after QKV)
    u16* wqb = (u16*)(ws + 8388608);
    u16* wkb = (u16*)(ws + 10485760);
    u16* wvb = (u16*)(ws + 12582912);
    u16* wob = (u16*)(ws + 14680064);
    u16* Qb  = (u16*)(ws + 16777216);
    u16* Kb  = (u16*)(ws + 25165824);
    u16* VTb = (u16*)(ws + 33554432);
    uint32_t* pmb = (uint32_t*)(ws + 41943040);   // 512 B mask bits
    u16* AOb = xb;

    cvtk<<<dim3(1024, 6), 256, 0, stream>>>(x, Wq, Wk, Wv, Wo, mask,
                                            xb, wqb, wkb, wvb, wob, pmb);
    gemm_qkv<<<dim3(256, 3), 256, 0, stream>>>(xb, wqb, wkb, wvb, Qb, Kb, VTb);
    attn_fwd<<<dim3(8, 32), 512, 0, stream>>>(Qb, Kb, VTb, pmb, AOb);
    gemm_out<<<dim3(256), 256, 0, stream>>>(AOb, wob, out);
}

// Round 8
// 126.484 us; speedup vs baseline: 1.1567x; 1.0038x over previous
//
#include <hip/hip_runtime.h>
#include <hip/hip_bf16.h>
#include <stdint.h>

#define D_MODEL 1024
#define NHEADS  16
#define HDIM    64
#define BB      2
#define TT      2048
#define MROWS   (BB*TT)      // 4096
#define GK      1024         // reduction dim for all projections

typedef __bf16 bf16_8 __attribute__((ext_vector_type(8)));
typedef __bf16 bf16_4 __attribute__((ext_vector_type(4)));
typedef float  f32x4  __attribute__((ext_vector_type(4)));
typedef unsigned short u16;

__device__ __forceinline__ u16 f2bf(float f) {
    union { float f; uint32_t u; } c; c.f = f;
    uint32_t u = c.u;
    uint32_t r = (u + 0x7FFFu + ((u >> 16) & 1u)) >> 16;
    return (u16)r;
}
__device__ __forceinline__ uint32_t pk2bf(float a, float b) {
    return (uint32_t)f2bf(a) | ((uint32_t)f2bf(b) << 16);
}

__device__ __forceinline__ void gload16(const void* g, void* l) {
    __builtin_amdgcn_global_load_lds(
        (const __attribute__((address_space(1))) unsigned int*)g,
        (__attribute__((address_space(3))) unsigned int*)l,
        16, 0, 0);
}

// ---------------------------------------------------------------- convert
__global__ __launch_bounds__(256) void cvtk(
    const float* __restrict__ x,  const float* __restrict__ wq,
    const float* __restrict__ wk, const float* __restrict__ wv,
    const float* __restrict__ wo, const unsigned char* __restrict__ mk,
    u16* __restrict__ xb,  u16* __restrict__ wqb, u16* __restrict__ wkb,
    u16* __restrict__ wvb, u16* __restrict__ wob, uint32_t* __restrict__ pmb)
{
    int z = blockIdx.y;
    if (z == 5) {   // pack padding mask bits: pmb[b*64 + i], bit j = mask[b][32i+j]
        int gi = blockIdx.x*256 + threadIdx.x;
        if (gi < BB*TT/32) {
            uint32_t wv = 0;
            #pragma unroll
            for (int j = 0; j < 32; ++j)
                wv |= (mk[gi*32 + j] ? 1u : 0u) << j;
            pmb[gi] = wv;
        }
        return;
    }
    const float* in; u16* out; int n4;
    switch (z) {
        case 0: in = x;  out = xb;  n4 = MROWS*D_MODEL/4; break;
        case 1: in = wq; out = wqb; n4 = D_MODEL*D_MODEL/4; break;
        case 2: in = wk; out = wkb; n4 = D_MODEL*D_MODEL/4; break;
        case 3: in = wv; out = wvb; n4 = D_MODEL*D_MODEL/4; break;
        default: in = wo; out = wob; n4 = D_MODEL*D_MODEL/4; break;
    }
    for (int i = blockIdx.x*256 + threadIdx.x; i < n4; i += 1024*256) {
        float4 v = ((const float4*)in)[i];
        uint2 pk;
        pk.x = pk2bf(v.x, v.y);
        pk.y = pk2bf(v.z, v.w);
        ((uint2*)out)[i] = pk;
    }
}

// ---------------------------------------------------------------- GEMM body
// C(128x128) tile of A(4096x1024) * B(1024x1024)^T, both bf16 row-major.
// MODE 0: scatter bf16 into (B,H,T,D)   [Q (scaled), K]
// MODE 1: swapped-operand MFMA; store bf16 into (B,H,D,T) coalesced  [V^T]
// MODE 2: f32 row-major (4096x1024)     [final out]
// NB=1: single-buffer, __syncthreads x2 (3 blocks/CU TLP -- for gemm_qkv).
// NB=2: raw-barrier pipelined double-buffer (1-block/CU launches -- gemm_out).
// blockIdx decode is XCD-aware: the 8 bn-blocks sharing one A-panel land on
// the same XCD (dispatch round-robins linear id % 8).
template<int MODE, int NB>
__device__ __forceinline__ void gemm_body(
    const u16* __restrict__ A, const u16* __restrict__ Bm,
    void* __restrict__ dst, float oscale)
{
    __shared__ u16 As[NB][128*64];
    __shared__ u16 Bs[NB][128*64];
    const int tid  = threadIdx.x;
    const int lane = tid & 63, w = tid >> 6;
    const int wr = w >> 1, wc = w & 1;
    const int g = lane >> 4, lr = lane & 15;
    // XCD-aware: x = xcd + 8*(bn + 8*bmh); bm = bmh*8 + xcd
    const int xcd = blockIdx.x & 7, qq_ = blockIdx.x >> 3;
    const int bn = qq_ & 7, bm = (qq_ >> 3)*8 + xcd;
    const int m0 = bm * 128, n0 = bn * 128;

    f32x4 acc[4][4];
    #pragma unroll
    for (int i = 0; i < 4; ++i)
        #pragma unroll
        for (int j = 0; j < 4; ++j)
            acc[i][j] = f32x4{0.f, 0.f, 0.f, 0.f};

    auto STG = [&](int kt, int buf) {
        int k0 = kt*64;
        #pragma unroll
        for (int r = 0; r < 4; ++r) {
            int o   = r*256 + tid;
            int row = o >> 3;
            int lc  = (o & 7) ^ (row & 7);
            gload16(A  + (size_t)(m0+row)*GK + k0 + lc*8,
                    (char*)&As[buf][0] + (size_t)(r*256 + w*64)*16);
            gload16(Bm + (size_t)(n0+row)*GK + k0 + lc*8,
                    (char*)&Bs[buf][0] + (size_t)(r*256 + w*64)*16);
        }
    };
    auto CMP = [&](const u16* Asc, const u16* Bsc) {
        #pragma unroll
        for (int ks = 0; ks < 2; ++ks) {
            bf16_8 af[4], bfr[4];
            #pragma unroll
            for (int mt = 0; mt < 4; ++mt) {
                int row = wr*64 + mt*16 + lr;
                int ch  = (ks*4 + g) ^ (row & 7);
                af[mt] = *(const bf16_8*)((const char*)Asc + row*128 + ch*16);
            }
            #pragma unroll
            for (int nt = 0; nt < 4; ++nt) {
                int row = wc*64 + nt*16 + lr;
                int ch  = (ks*4 + g) ^ (row & 7);
                bfr[nt] = *(const bf16_8*)((const char*)Bsc + row*128 + ch*16);
            }
            #pragma unroll
            for (int mt = 0; mt < 4; ++mt)
                #pragma unroll
                for (int nt = 0; nt < 4; ++nt) {
                    if (MODE == 1)
                        acc[mt][nt] = __builtin_amdgcn_mfma_f32_16x16x32_bf16(
                            bfr[nt], af[mt], acc[mt][nt], 0, 0, 0);
                    else
                        acc[mt][nt] = __builtin_amdgcn_mfma_f32_16x16x32_bf16(
                            af[mt], bfr[nt], acc[mt][nt], 0, 0, 0);
                }
        }
    };

    if (NB == 2) {
        STG(0, 0);
        for (int kt = 0; kt < 16; ++kt) {
            asm volatile("s_waitcnt vmcnt(0)" ::: "memory");
            __builtin_amdgcn_s_barrier();
            if (kt + 1 < 16) STG(kt+1, (kt+1) & 1);
            __builtin_amdgcn_s_setprio(1);
            CMP(&As[kt & 1][0], &Bs[kt & 1][0]);
            __builtin_amdgcn_s_setprio(0);
        }
    } else {
        for (int kt = 0; kt < 16; ++kt) {
            STG(kt, 0);
            __syncthreads();
            CMP(&As[0][0], &Bs[0][0]);
            __syncthreads();
        }
    }

    #pragma unroll
    for (int mt = 0; mt < 4; ++mt) {
        #pragma unroll
        for (int nt = 0; nt < 4; ++nt) {
            #pragma unroll
            for (int r = 0; r < 4; ++r) {
                float v = acc[mt][nt][r];
                if (MODE == 2) {
                    int row = m0 + wr*64 + mt*16 + g*4 + r;
                    int col = n0 + wc*64 + nt*16 + lr;
                    ((float*)dst)[(size_t)row*D_MODEL + col] = v;
                } else if (MODE == 0) {
                    int row = m0 + wr*64 + mt*16 + g*4 + r;   // m: (b,t)
                    int col = n0 + wc*64 + nt*16 + lr;        // n: (h,d)
                    int b = row >> 11, t = row & (TT-1);
                    int h = col >> 6,  d = col & 63;
                    ((u16*)dst)[(((size_t)(b*NHEADS + h)*TT + t)*HDIM + d)] = f2bf(v*oscale);
                } else {  // MODE 1: acc row = n-side (h,d), col = m-side (b,t)
                    int nrow = n0 + wc*64 + nt*16 + g*4 + r;  // n: (h,d)
                    int mcol = m0 + wr*64 + mt*16 + lr;       // m: (b,t)
                    int h = nrow >> 6,  d = nrow & 63;
                    int b = mcol >> 11, t = mcol & (TT-1);
                    ((u16*)dst)[(((size_t)(b*NHEADS + h)*HDIM + d)*TT + t)] = f2bf(v);
                }
            }
        }
    }
}

__global__ __launch_bounds__(256) void gemm_qkv(
    const u16* __restrict__ xb,
    const u16* __restrict__ wqb, const u16* __restrict__ wkb, const u16* __restrict__ wvb,
    u16* __restrict__ Qb, u16* __restrict__ Kb, u16* __restrict__ VTb)
{
    int z = blockIdx.y;
    if (z == 0)      gemm_body<0,1>(xb, wqb, Qb, 0.18033688f);  // (1/8)*log2(e)
    else if (z == 1) gemm_body<0,1>(xb, wkb, Kb, 1.0f);
    else             gemm_body<1,1>(xb, wvb, VTb, 1.0f);
}

__global__ __launch_bounds__(256) void gemm_out(
    const u16* __restrict__ AOb, const u16* __restrict__ wob, float* __restrict__ out)
{
    gemm_body<2,2>(AOb, wob, out, 1.0f);
}

// ---------------------------------------------------------------- attention
// grid (8, 32) = 256 blocks, 512 threads = 8 waves; ~66.5 KB LDS -> 2 blocks/CU.
// Block owns complementary q-tile pair {qtH = 15-p, qtL = p} -> constant work.
// Wave owns 16 heavy rows + 16 light rows (light reversed: per-wave ~33 units).
// bh = 4*blockIdx.x + (y&3): all 8 blocks of a bh land on one XCD (L2 reuse).
// KVBLK=64, 3 LDS buffers, depth-2 prefetch, counted vmcnt(2).
// P region is SINGLE-qg sized: per tile, qg0 {softmax,Pwrite,PV} completes
// before qg1 overwrites it (DS ops are in-order per wave).
__global__ __launch_bounds__(512, 2) void attn_fwd(
    const u16* __restrict__ Qb, const u16* __restrict__ Kb,
    const u16* __restrict__ VTb, const uint32_t* __restrict__ pmb,
    u16* __restrict__ AO)
{
    __shared__ u16 Ks[3][64*64];      // 24 KB
    __shared__ u16 Vs[3][64*64];      // 24 KB
    __shared__ u16 Pl[8][1152];       // 18 KB: per-wave P (one qg) / epilogue scratch
    __shared__ uint32_t Ml[64];       // mask bits for this batch

    const int tid = threadIdx.x, lane = tid & 63, w = tid >> 6;
    const int g = lane >> 4, lr = lane & 15;
    const int x = blockIdx.x, y = blockIdx.y;
    const int bh = x*4 + (y & 3), p = y >> 2;
    const int b = bh >> 4, h = bh & 15;
    const int qtH = 15 - p, qtL = p;
    const int qlo0 = qtH*128 + w*16;            // heavy rows
    const int qlo1 = qtL*128 + (7-w)*16;        // light rows (reversed)
    const int ta0  = (qlo0 + 15) >> 6;          // last kv tile for heavy
    const int ta1  = (qlo1 + 15) >> 6;          // last kv tile for light
    const int nt   = 2*qtH + 2;

    const u16* Qh = Qb  + (size_t)bh*TT*HDIM;
    const u16* Kh = Kb  + (size_t)bh*TT*HDIM;
    const u16* Vh = VTb + (size_t)bh*HDIM*TT;
    char* Pw = (char*)&Pl[w][0];

    if (tid < 64) Ml[tid] = pmb[b*(TT/32) + tid];

    // Q B-frags (pre-scaled by log2e/8): qf[qg][dc] = Q[qlo+lr][dc*32+g*8..]
    bf16_8 qf[2][2];
    #pragma unroll
    for (int dc = 0; dc < 2; ++dc) {
        qf[0][dc] = *(const bf16_8*)(Qh + (size_t)(qlo0+lr)*HDIM + dc*32 + g*8);
        qf[1][dc] = *(const bf16_8*)(Qh + (size_t)(qlo1+lr)*HDIM + dc*32 + g*8);
    }

    f32x4 o[2][4];                    // O^T: o[qg][dt][r] = O[dt*16+4g+r][q=qlo+lr]
    #pragma unroll
    for (int qg = 0; qg < 2; ++qg)
        #pragma unroll
        for (int i = 0; i < 4; ++i) o[qg][i] = f32x4{0.f, 0.f, 0.f, 0.f};
    float m_run[2] = {-1e30f, -1e30f}, l_run[2] = {0.f, 0.f};

    auto STAGE = [&](int t, int buf) {
        int kv0 = t*64;
        int row = tid >> 3;                        // 0..63
        int lc  = (tid & 7) ^ (row & 7);
        char* lk = (char*)&Ks[buf][0] + (size_t)(w*64)*16;   // wave-uniform base
        char* lv = (char*)&Vs[buf][0] + (size_t)(w*64)*16;
        gload16(Kh + (size_t)(kv0+row)*HDIM + lc*8, lk);
        gload16(Vh + (size_t)row*TT + kv0 + lc*8, lv);
    };

    STAGE(0, 0);          // nt >= 2 always
    STAGE(1, 1);

    int cur = 0;
    for (int t = 0; t < nt; ++t) {
        if (t + 1 < nt) asm volatile("s_waitcnt vmcnt(2) lgkmcnt(0)" ::: "memory");
        else            asm volatile("s_waitcnt vmcnt(0) lgkmcnt(0)" ::: "memory");
        __builtin_amdgcn_s_barrier();
        if (t + 2 < nt) { int nb = cur + 2; if (nb >= 3) nb -= 3; STAGE(t+2, nb); }

        const bool a0 = (t <= ta0), a1 = (t <= ta1);
        if (a0 || a1) {
            const int kv0 = t*64;
            const u16* Kc = &Ks[cur][0];
            const u16* Vc = &Vs[cur][0];

            // ---- QK^T swapped: s[qg][kvb] lane: q=qlo+lr, kv=kv0+16kvb+4g+reg
            f32x4 s[2][4];
            __builtin_amdgcn_s_setprio(1);
            #pragma unroll
            for (int kvb = 0; kvb < 4; ++kvb) {
                int row = kvb*16 + lr;
                int sw  = row & 7;
                bf16_8 k0 = *(const bf16_8*)(Kc + row*64 + ((g    ) ^ sw)*8);
                bf16_8 k1 = *(const bf16_8*)(Kc + row*64 + ((4 + g) ^ sw)*8);
                if (a0) {
                    f32x4 z = f32x4{0.f, 0.f, 0.f, 0.f};
                    z = __builtin_amdgcn_mfma_f32_16x16x32_bf16(k0, qf[0][0], z, 0, 0, 0);
                    z = __builtin_amdgcn_mfma_f32_16x16x32_bf16(k1, qf[0][1], z, 0, 0, 0);
                    s[0][kvb] = z;
                }
                if (a1) {
                    f32x4 z = f32x4{0.f, 0.f, 0.f, 0.f};
                    z = __builtin_amdgcn_mfma_f32_16x16x32_bf16(k0, qf[1][0], z, 0, 0, 0);
                    z = __builtin_amdgcn_mfma_f32_16x16x32_bf16(k1, qf[1][1], z, 0, 0, 0);
                    s[1][kvb] = z;
                }
            }
            __builtin_amdgcn_s_setprio(0);

            // ---- V^T A-frags (LDS; latency hides under softmax)
            bf16_8 vf[4][2];
            #pragma unroll
            for (int dt = 0; dt < 4; ++dt)
                #pragma unroll
                for (int hh = 0; hh < 2; ++hh)
                    vf[dt][hh] = *(const bf16_8*)(Vc + (dt*16+lr)*64 + ((hh*4+g) ^ (lr&7))*8);

            uint64_t m64 = (uint64_t)Ml[2*t] | ((uint64_t)Ml[2*t+1] << 32);

            // ---- per-qg: mask, softmax (exp2, defer-max), P-write, PV
            // (single P region per wave, reused qg0 -> qg1; DS in-order per wave)
            #pragma unroll
            for (int qg = 0; qg < 2; ++qg) {
                if (!(qg == 0 ? a0 : a1)) continue;
                const int qlo = qg ? qlo1 : qlo0;
                const int ta  = qg ? ta1  : ta0;
                if (m64) {
                    #pragma unroll
                    for (int kvb = 0; kvb < 4; ++kvb) {
                        uint32_t nib = (uint32_t)(m64 >> (kvb*16 + 4*g)) & 0xFu;
                        #pragma unroll
                        for (int r = 0; r < 4; ++r)
                            if ((nib >> r) & 1) s[qg][kvb][r] = -1e30f;
                    }
                }
                if (t == ta) {
                    int q = qlo + lr;
                    #pragma unroll
                    for (int kvb = 0; kvb < 4; ++kvb) {
                        int kvb0 = kv0 + kvb*16 + 4*g;
                        #pragma unroll
                        for (int r = 0; r < 4; ++r)
                            if (kvb0 + r > q) s[qg][kvb][r] = -1e30f;
                    }
                }
                float t0 = fmaxf(fmaxf(s[qg][0][0], s[qg][0][1]), fmaxf(s[qg][0][2], s[qg][0][3]));
                float t1 = fmaxf(fmaxf(s[qg][1][0], s[qg][1][1]), fmaxf(s[qg][1][2], s[qg][1][3]));
                float t2 = fmaxf(fmaxf(s[qg][2][0], s[qg][2][1]), fmaxf(s[qg][2][2], s[qg][2][3]));
                float t3 = fmaxf(fmaxf(s[qg][3][0], s[qg][3][1]), fmaxf(s[qg][3][2], s[qg][3][3]));
                float mx = fmaxf(fmaxf(t0, t1), fmaxf(t2, t3));
                mx = fmaxf(mx, __shfl_xor(mx, 16));
                mx = fmaxf(mx, __shfl_xor(mx, 32));
                if (__any(mx > m_run[qg] + 8.f)) {
                    float nm = fmaxf(m_run[qg], mx);
                    float fs = __builtin_amdgcn_exp2f(m_run[qg] - nm);
                    #pragma unroll
                    for (int dt = 0; dt < 4; ++dt)
                        #pragma unroll
                        for (int r = 0; r < 4; ++r)
                            o[qg][dt][r] *= fs;
                    l_run[qg] *= fs;
                    m_run[qg] = nm;
                }
                #pragma unroll
                for (int kvb = 0; kvb < 4; ++kvb)
                    #pragma unroll
                    for (int r = 0; r < 4; ++r)
                        s[qg][kvb][r] = __builtin_amdgcn_exp2f(s[qg][kvb][r] - m_run[qg]);
                float p0 = (s[qg][0][0] + s[qg][0][1]) + (s[qg][0][2] + s[qg][0][3]);
                float p1 = (s[qg][1][0] + s[qg][1][1]) + (s[qg][1][2] + s[qg][1][3]);
                float p2 = (s[qg][2][0] + s[qg][2][1]) + (s[qg][2][2] + s[qg][2][3]);
                float p3 = (s[qg][3][0] + s[qg][3][1]) + (s[qg][3][2] + s[qg][3][3]);
                float ps = (p0 + p1) + (p2 + p3);
                ps += __shfl_xor(ps, 16);
                ps += __shfl_xor(ps, 32);
                l_run[qg] += ps;
                #pragma unroll
                for (int kvb = 0; kvb < 4; ++kvb) {
                    bf16_4 pk;
                    pk[0] = (__bf16)s[qg][kvb][0]; pk[1] = (__bf16)s[qg][kvb][1];
                    pk[2] = (__bf16)s[qg][kvb][2]; pk[3] = (__bf16)s[qg][kvb][3];
                    *(bf16_4*)(Pw + lr*144 + kvb*32 + g*8) = pk;
                }
                asm volatile("s_waitcnt lgkmcnt(0)" ::: "memory");
                __builtin_amdgcn_sched_barrier(0);

                // ---- PV swapped: O^T += V^T(A) x P(B)
                __builtin_amdgcn_s_setprio(1);
                #pragma unroll
                for (int hh = 0; hh < 2; ++hh) {
                    bf16_8 pa = *(const bf16_8*)(Pw + lr*144 + hh*64 + g*16);
                    #pragma unroll
                    for (int dt = 0; dt < 4; ++dt)
                        o[qg][dt] = __builtin_amdgcn_mfma_f32_16x16x32_bf16(
                            vf[dt][hh], pa, o[qg][dt], 0, 0, 0);
                }
                __builtin_amdgcn_s_setprio(0);
            }
        }

        ++cur; if (cur == 3) cur = 0;
    }

    // ---- epilogue: per-lane divide, LDS transpose (per qg, region reused),
    // coalesced 128B row stores
    #pragma unroll
    for (int qg = 0; qg < 2; ++qg) {
        float linv = (l_run[qg] > 0.f) ? 1.f/l_run[qg] : 0.f;
        u16* ot = (u16*)Pw;                        // [d 64][q 16] stride 17
        #pragma unroll
        for (int dt = 0; dt < 4; ++dt)
            #pragma unroll
            for (int r = 0; r < 4; ++r)
                ot[(dt*16 + 4*g + r)*17 + lr] = f2bf(o[qg][dt][r]*linv);
        asm volatile("s_waitcnt lgkmcnt(0)" ::: "memory");
        __builtin_amdgcn_sched_barrier(0);
        const int qlo = qg ? qlo1 : qlo0;
        #pragma unroll
        for (int qq = 0; qq < 16; ++qq)
            AO[((size_t)(b*TT + qlo + qq))*D_MODEL + h*HDIM + lane] = ot[lane*17 + qq];
        asm volatile("s_waitcnt lgkmcnt(0)" ::: "memory");   // reads done before qg1 overwrites
        __builtin_amdgcn_sched_barrier(0);
    }
}

// ---------------------------------------------------------------- launch
extern "C" void kernel_launch(void* const* d_in, const int* in_sizes, int n_in,
                              void* d_out, int out_size, void* d_ws, size_t ws_size,
                              hipStream_t stream)
{
    const float* x  = (const float*)d_in[0];
    const unsigned char* mask = (const unsigned char*)d_in[1];
    const float* Wq = (const float*)d_in[2];
    const float* Wk = (const float*)d_in[3];
    const float* Wv = (const float*)d_in[4];
    const float* Wo = (const float*)d_in[5];
    float* out = (float*)d_out;

    char* ws = (char*)d_ws;
    u16* xb  = (u16*)(ws + 0);          // 8 MB (reused as AO after QKV)
    u16* wqb = (u16*)(ws + 8388608);
    u16* wkb = (u16*)(ws + 10485760);
    u16* wvb = (u16*)(ws + 12582912);
    u16* wob = (u16*)(ws + 14680064);
    u16* Qb  = (u16*)(ws + 16777216);
    u16* Kb  = (u16*)(ws + 25165824);
    u16* VTb = (u16*)(ws + 33554432);
    uint32_t* pmb = (uint32_t*)(ws + 41943040);   // 512 B mask bits
    u16* AOb = xb;

    cvtk<<<dim3(1024, 6), 256, 0, stream>>>(x, Wq, Wk, Wv, Wo, mask,
                                            xb, wqb, wkb, wvb, wob, pmb);
    gemm_qkv<<<dim3(256, 3), 256, 0, stream>>>(xb, wqb, wkb, wvb, Qb, Kb, VTb);
    attn_fwd<<<dim3(8, 32), 512, 0, stream>>>(Qb, Kb, VTb, pmb, AOb);
    gemm_out<<<dim3(256), 256, 0, stream>>>(AOb, wob, out);
}

// Round 9
// 113.346 us; speedup vs baseline: 1.2908x; 1.1159x over previous
//
#include <hip/hip_runtime.h>
#include <hip/hip_bf16.h>
#include <stdint.h>

#define D_MODEL 1024
#define NHEADS  16
#define HDIM    64
#define BB      2
#define TT      2048
#define MROWS   (BB*TT)      // 4096
#define GK      1024         // reduction dim for all projections

typedef __bf16 bf16_8 __attribute__((ext_vector_type(8)));
typedef __bf16 bf16_4 __attribute__((ext_vector_type(4)));
typedef float  f32x4  __attribute__((ext_vector_type(4)));
typedef unsigned short u16;

__device__ __forceinline__ u16 f2bf(float f) {
    union { float f; uint32_t u; } c; c.f = f;
    uint32_t u = c.u;
    uint32_t r = (u + 0x7FFFu + ((u >> 16) & 1u)) >> 16;
    return (u16)r;
}
__device__ __forceinline__ uint32_t pk2bf(float a, float b) {
    return (uint32_t)f2bf(a) | ((uint32_t)f2bf(b) << 16);
}

__device__ __forceinline__ void gload16(const void* g, void* l) {
    __builtin_amdgcn_global_load_lds(
        (const __attribute__((address_space(1))) unsigned int*)g,
        (__attribute__((address_space(3))) unsigned int*)l,
        16, 0, 0);
}

// ---------------------------------------------------------------- convert
__global__ __launch_bounds__(256) void cvtk(
    const float* __restrict__ x,  const float* __restrict__ wq,
    const float* __restrict__ wk, const float* __restrict__ wv,
    const float* __restrict__ wo, const unsigned char* __restrict__ mk,
    u16* __restrict__ xb,  u16* __restrict__ wqb, u16* __restrict__ wkb,
    u16* __restrict__ wvb, u16* __restrict__ wob, uint32_t* __restrict__ pmb)
{
    int z = blockIdx.y;
    if (z == 5) {   // pack padding mask bits: pmb[b*64 + i], bit j = mask[b][32i+j]
        int gi = blockIdx.x*256 + threadIdx.x;
        if (gi < BB*TT/32) {
            uint32_t wv = 0;
            #pragma unroll
            for (int j = 0; j < 32; ++j)
                wv |= (mk[gi*32 + j] ? 1u : 0u) << j;
            pmb[gi] = wv;
        }
        return;
    }
    const float* in; u16* out; int n4;
    switch (z) {
        case 0: in = x;  out = xb;  n4 = MROWS*D_MODEL/4; break;
        case 1: in = wq; out = wqb; n4 = D_MODEL*D_MODEL/4; break;
        case 2: in = wk; out = wkb; n4 = D_MODEL*D_MODEL/4; break;
        case 3: in = wv; out = wvb; n4 = D_MODEL*D_MODEL/4; break;
        default: in = wo; out = wob; n4 = D_MODEL*D_MODEL/4; break;
    }
    for (int i = blockIdx.x*256 + threadIdx.x; i < n4; i += 1024*256) {
        float4 v = ((const float4*)in)[i];
        uint2 pk;
        pk.x = pk2bf(v.x, v.y);
        pk.y = pk2bf(v.z, v.w);
        ((uint2*)out)[i] = pk;
    }
}

// ---------------------------------------------------------------- GEMM body
// C(128x128) tile of A(4096x1024) * B(1024x1024)^T, both bf16 row-major.
// MODE 0: scatter bf16 into (B,H,T,D)   [Q (scaled), K]
// MODE 1: swapped-operand MFMA; store bf16 into (B,H,D,T) coalesced  [V^T]
// MODE 2: f32 row-major (4096x1024)     [final out]
// NB=1: single-buffer, __syncthreads x2 (3 blocks/CU TLP -- for gemm_qkv).
// NB=2: raw-barrier pipelined double-buffer (1-block/CU launches -- gemm_out).
template<int MODE, int NB>
__device__ __forceinline__ void gemm_body(
    const u16* __restrict__ A, const u16* __restrict__ Bm,
    void* __restrict__ dst, float oscale)
{
    __shared__ u16 As[NB][128*64];
    __shared__ u16 Bs[NB][128*64];
    const int tid  = threadIdx.x;
    const int lane = tid & 63, w = tid >> 6;
    const int wr = w >> 1, wc = w & 1;
    const int g = lane >> 4, lr = lane & 15;
    // XCD-aware: x = xcd + 8*(bn + 8*bmh); bm = bmh*8 + xcd
    const int xcd = blockIdx.x & 7, qq_ = blockIdx.x >> 3;
    const int bn = qq_ & 7, bm = (qq_ >> 3)*8 + xcd;
    const int m0 = bm * 128, n0 = bn * 128;

    f32x4 acc[4][4];
    #pragma unroll
    for (int i = 0; i < 4; ++i)
        #pragma unroll
        for (int j = 0; j < 4; ++j)
            acc[i][j] = f32x4{0.f, 0.f, 0.f, 0.f};

    auto STG = [&](int kt, int buf) {
        int k0 = kt*64;
        #pragma unroll
        for (int r = 0; r < 4; ++r) {
            int o   = r*256 + tid;
            int row = o >> 3;
            int lc  = (o & 7) ^ (row & 7);
            gload16(A  + (size_t)(m0+row)*GK + k0 + lc*8,
                    (char*)&As[buf][0] + (size_t)(r*256 + w*64)*16);
            gload16(Bm + (size_t)(n0+row)*GK + k0 + lc*8,
                    (char*)&Bs[buf][0] + (size_t)(r*256 + w*64)*16);
        }
    };
    auto CMP = [&](const u16* Asc, const u16* Bsc) {
        #pragma unroll
        for (int ks = 0; ks < 2; ++ks) {
            bf16_8 af[4], bfr[4];
            #pragma unroll
            for (int mt = 0; mt < 4; ++mt) {
                int row = wr*64 + mt*16 + lr;
                int ch  = (ks*4 + g) ^ (row & 7);
                af[mt] = *(const bf16_8*)((const char*)Asc + row*128 + ch*16);
            }
            #pragma unroll
            for (int nt = 0; nt < 4; ++nt) {
                int row = wc*64 + nt*16 + lr;
                int ch  = (ks*4 + g) ^ (row & 7);
                bfr[nt] = *(const bf16_8*)((const char*)Bsc + row*128 + ch*16);
            }
            #pragma unroll
            for (int mt = 0; mt < 4; ++mt)
                #pragma unroll
                for (int nt = 0; nt < 4; ++nt) {
                    if (MODE == 1)
                        acc[mt][nt] = __builtin_amdgcn_mfma_f32_16x16x32_bf16(
                            bfr[nt], af[mt], acc[mt][nt], 0, 0, 0);
                    else
                        acc[mt][nt] = __builtin_amdgcn_mfma_f32_16x16x32_bf16(
                            af[mt], bfr[nt], acc[mt][nt], 0, 0, 0);
                }
        }
    };

    if (NB == 2) {
        STG(0, 0);
        for (int kt = 0; kt < 16; ++kt) {
            asm volatile("s_waitcnt vmcnt(0)" ::: "memory");
            __builtin_amdgcn_s_barrier();
            if (kt + 1 < 16) STG(kt+1, (kt+1) & 1);
            __builtin_amdgcn_s_setprio(1);
            CMP(&As[kt & 1][0], &Bs[kt & 1][0]);
            __builtin_amdgcn_s_setprio(0);
        }
    } else {
        for (int kt = 0; kt < 16; ++kt) {
            STG(kt, 0);
            __syncthreads();
            CMP(&As[0][0], &Bs[0][0]);
            __syncthreads();
        }
    }

    #pragma unroll
    for (int mt = 0; mt < 4; ++mt) {
        #pragma unroll
        for (int nt = 0; nt < 4; ++nt) {
            #pragma unroll
            for (int r = 0; r < 4; ++r) {
                float v = acc[mt][nt][r];
                if (MODE == 2) {
                    int row = m0 + wr*64 + mt*16 + g*4 + r;
                    int col = n0 + wc*64 + nt*16 + lr;
                    ((float*)dst)[(size_t)row*D_MODEL + col] = v;
                } else if (MODE == 0) {
                    int row = m0 + wr*64 + mt*16 + g*4 + r;   // m: (b,t)
                    int col = n0 + wc*64 + nt*16 + lr;        // n: (h,d)
                    int b = row >> 11, t = row & (TT-1);
                    int h = col >> 6,  d = col & 63;
                    ((u16*)dst)[(((size_t)(b*NHEADS + h)*TT + t)*HDIM + d)] = f2bf(v*oscale);
                } else {  // MODE 1: acc row = n-side (h,d), col = m-side (b,t)
                    int nrow = n0 + wc*64 + nt*16 + g*4 + r;  // n: (h,d)
                    int mcol = m0 + wr*64 + mt*16 + lr;       // m: (b,t)
                    int h = nrow >> 6,  d = nrow & 63;
                    int b = mcol >> 11, t = mcol & (TT-1);
                    ((u16*)dst)[(((size_t)(b*NHEADS + h)*HDIM + d)*TT + t)] = f2bf(v);
                }
            }
        }
    }
}

__global__ __launch_bounds__(256) void gemm_qkv(
    const u16* __restrict__ xb,
    const u16* __restrict__ wqb, const u16* __restrict__ wkb, const u16* __restrict__ wvb,
    u16* __restrict__ Qb, u16* __restrict__ Kb, u16* __restrict__ VTb)
{
    int z = blockIdx.y;
    if (z == 0)      gemm_body<0,1>(xb, wqb, Qb, 0.18033688f);  // (1/8)*log2(e)
    else if (z == 1) gemm_body<0,1>(xb, wkb, Kb, 1.0f);
    else             gemm_body<1,1>(xb, wvb, VTb, 1.0f);
}

__global__ __launch_bounds__(256) void gemm_out(
    const u16* __restrict__ AOb, const u16* __restrict__ wob, float* __restrict__ out)
{
    gemm_body<2,2>(AOb, wob, out, 1.0f);
}

// ---------------------------------------------------------------- attention
// grid (32 bh, 16 pairs) = 512 blocks of 8 waves; 58.25 KB LDS -> 2 blocks/CU
// = 16 waves/CU. Each wave owns ONE 16-row q-group: waves 0-3 -> heavy tile
// qtH = 31-p; waves 4-7 -> light tile qtL = p (64-row tiles). nt = qtH+1.
// p remapped so dispatch puts (p, 15-p) on the same CU (49 iters per CU).
// bh = blockIdx.x: all 16 pair-blocks of a bh land on XCD bh%8 (L2 reuse).
// K: 3 buffers depth-2 prefetch; V: 2 buffers depth-1 (consumed late).
// Per iter: wait vmcnt(1) [K(t),V(t) done; K(t+1) in flight]; barrier;
// issue V(t+1) then K(t+2); compute.
__global__ __launch_bounds__(512, 4) void attn_fwd(
    const u16* __restrict__ Qb, const u16* __restrict__ Kb,
    const u16* __restrict__ VTb, const uint32_t* __restrict__ pmb,
    u16* __restrict__ AO)
{
    __shared__ u16 Ks[3][64*64];      // 24 KB
    __shared__ u16 Vs[2][64*64];      // 16 KB
    __shared__ u16 Pl[8][1152];       // 18 KB per-wave P / epilogue scratch
    __shared__ uint32_t Ml[64];       // mask bits for this batch

    const int tid = threadIdx.x, lane = tid & 63, w = tid >> 6;
    const int g = lane >> 4, lr = lane & 15;
    const int bh = blockIdx.x, yb = blockIdx.y;
    const int p  = (yb < 8) ? yb : 23 - yb;          // pair remap: CU gets (p,15-p)
    const int b = bh >> 4, h = bh & 15;
    const int qtH = 31 - p;
    const bool heavy = (w < 4);
    const int qlo = heavy ? (qtH*64 + w*16) : (p*64 + (w-4)*16);
    const int ta  = heavy ? qtH : p;                 // wave's last kv tile
    const int nt  = qtH + 1;

    const u16* Qh = Qb  + (size_t)bh*TT*HDIM;
    const u16* Kh = Kb  + (size_t)bh*TT*HDIM;
    const u16* Vh = VTb + (size_t)bh*HDIM*TT;
    char* Pw = (char*)&Pl[w][0];

    if (tid < 64) Ml[tid] = pmb[b*(TT/32) + tid];

    // Q B-frags (pre-scaled by log2e/8): qf[dc] = Q[qlo+lr][dc*32+g*8..]
    bf16_8 qf[2];
    #pragma unroll
    for (int dc = 0; dc < 2; ++dc)
        qf[dc] = *(const bf16_8*)(Qh + (size_t)(qlo+lr)*HDIM + dc*32 + g*8);

    f32x4 o[4];                       // O^T: o[dt][r] = O[dt*16+4g+r][q=qlo+lr]
    #pragma unroll
    for (int i = 0; i < 4; ++i) o[i] = f32x4{0.f, 0.f, 0.f, 0.f};
    float m_run = -1e30f, l_run = 0.f;

    // cooperative stages: 512 threads x 16B = one 8KB tile per call
    auto STAGE_K = [&](int t, int buf) {
        int kv0 = t*64;
        int row = tid >> 3;                        // 0..63 (kv)
        int lc  = (tid & 7) ^ (row & 7);
        gload16(Kh + (size_t)(kv0+row)*HDIM + lc*8,
                (char*)&Ks[buf][0] + (size_t)(w*64)*16);
    };
    auto STAGE_V = [&](int t, int buf) {
        int kv0 = t*64;
        int row = tid >> 3;                        // 0..63 (d)
        int lc  = (tid & 7) ^ (row & 7);
        gload16(Vh + (size_t)row*TT + kv0 + lc*8,
                (char*)&Vs[buf][0] + (size_t)(w*64)*16);
    };

    // prologue: [K0, V0, K1] in flight (issue order matters for vmcnt)
    STAGE_K(0, 0);
    STAGE_V(0, 0);
    STAGE_K(1, 1);

    int kb = 0;                                    // K buffer of tile t
    for (int t = 0; t < nt; ++t) {
        if (t + 1 < nt) asm volatile("s_waitcnt vmcnt(1) lgkmcnt(0)" ::: "memory");
        else            asm volatile("s_waitcnt vmcnt(0) lgkmcnt(0)" ::: "memory");
        __builtin_amdgcn_s_barrier();
        if (t + 1 < nt) STAGE_V(t+1, (t+1) & 1);
        if (t + 2 < nt) { int nk = kb + 2; if (nk >= 3) nk -= 3; STAGE_K(t+2, nk); }

        if (t <= ta) {
            const int kv0 = t*64;
            const u16* Kc = &Ks[kb][0];
            const u16* Vc = &Vs[t & 1][0];

            // ---- QK^T swapped: s[kvb] lane: q=qlo+lr, kv=kv0+16kvb+4g+reg
            f32x4 s[4];
            __builtin_amdgcn_s_setprio(1);
            #pragma unroll
            for (int kvb = 0; kvb < 4; ++kvb) {
                int row = kvb*16 + lr;
                int sw  = row & 7;
                bf16_8 k0 = *(const bf16_8*)(Kc + row*64 + ((g    ) ^ sw)*8);
                bf16_8 k1 = *(const bf16_8*)(Kc + row*64 + ((4 + g) ^ sw)*8);
                f32x4 z = f32x4{0.f, 0.f, 0.f, 0.f};
                z = __builtin_amdgcn_mfma_f32_16x16x32_bf16(k0, qf[0], z, 0, 0, 0);
                z = __builtin_amdgcn_mfma_f32_16x16x32_bf16(k1, qf[1], z, 0, 0, 0);
                s[kvb] = z;
            }
            __builtin_amdgcn_s_setprio(0);

            // ---- V^T A-frags (LDS; latency hides under softmax)
            bf16_8 vf[4][2];
            #pragma unroll
            for (int dt = 0; dt < 4; ++dt)
                #pragma unroll
                for (int hh = 0; hh < 2; ++hh)
                    vf[dt][hh] = *(const bf16_8*)(Vc + (dt*16+lr)*64 + ((hh*4+g) ^ (lr&7))*8);

            // ---- padding mask from LDS bits (skipped when all-clear)
            uint64_t m64 = (uint64_t)Ml[2*t] | ((uint64_t)Ml[2*t+1] << 32);
            if (m64) {
                #pragma unroll
                for (int kvb = 0; kvb < 4; ++kvb) {
                    uint32_t nib = (uint32_t)(m64 >> (kvb*16 + 4*g)) & 0xFu;
                    #pragma unroll
                    for (int r = 0; r < 4; ++r)
                        if ((nib >> r) & 1) s[kvb][r] = -1e30f;
                }
            }
            // ---- causal mask (diagonal tile only)
            if (t == ta) {
                int q = qlo + lr;
                #pragma unroll
                for (int kvb = 0; kvb < 4; ++kvb) {
                    int kvb0 = kv0 + kvb*16 + 4*g;
                    #pragma unroll
                    for (int r = 0; r < 4; ++r)
                        if (kvb0 + r > q) s[kvb][r] = -1e30f;
                }
            }

            // ---- online softmax (exp2 domain) with defer-max THR=8
            float t0 = fmaxf(fmaxf(s[0][0], s[0][1]), fmaxf(s[0][2], s[0][3]));
            float t1 = fmaxf(fmaxf(s[1][0], s[1][1]), fmaxf(s[1][2], s[1][3]));
            float t2 = fmaxf(fmaxf(s[2][0], s[2][1]), fmaxf(s[2][2], s[2][3]));
            float t3 = fmaxf(fmaxf(s[3][0], s[3][1]), fmaxf(s[3][2], s[3][3]));
            float mx = fmaxf(fmaxf(t0, t1), fmaxf(t2, t3));
            mx = fmaxf(mx, __shfl_xor(mx, 16));
            mx = fmaxf(mx, __shfl_xor(mx, 32));
            if (__any(mx > m_run + 8.f)) {
                float nm = fmaxf(m_run, mx);
                float fs = __builtin_amdgcn_exp2f(m_run - nm);
                #pragma unroll
                for (int dt = 0; dt < 4; ++dt)
                    #pragma unroll
                    for (int r = 0; r < 4; ++r)
                        o[dt][r] *= fs;
                l_run *= fs;
                m_run = nm;
            }
            #pragma unroll
            for (int kvb = 0; kvb < 4; ++kvb)
                #pragma unroll
                for (int r = 0; r < 4; ++r)
                    s[kvb][r] = __builtin_amdgcn_exp2f(s[kvb][r] - m_run);
            float p0 = (s[0][0] + s[0][1]) + (s[0][2] + s[0][3]);
            float p1 = (s[1][0] + s[1][1]) + (s[1][2] + s[1][3]);
            float p2 = (s[2][0] + s[2][1]) + (s[2][2] + s[2][3]);
            float p3 = (s[3][0] + s[3][1]) + (s[3][2] + s[3][3]);
            float ps = (p0 + p1) + (p2 + p3);
            ps += __shfl_xor(ps, 16);
            ps += __shfl_xor(ps, 32);
            l_run += ps;

            // ---- P -> LDS (per-wave; v_cvt_pk_bf16_f32 + ds_write_b64)
            #pragma unroll
            for (int kvb = 0; kvb < 4; ++kvb) {
                bf16_4 pk;
                pk[0] = (__bf16)s[kvb][0]; pk[1] = (__bf16)s[kvb][1];
                pk[2] = (__bf16)s[kvb][2]; pk[3] = (__bf16)s[kvb][3];
                *(bf16_4*)(Pw + lr*144 + kvb*32 + g*8) = pk;
            }
            asm volatile("s_waitcnt lgkmcnt(0)" ::: "memory");
            __builtin_amdgcn_sched_barrier(0);

            // ---- PV swapped: O^T += V^T(A) x P(B)
            __builtin_amdgcn_s_setprio(1);
            #pragma unroll
            for (int hh = 0; hh < 2; ++hh) {
                bf16_8 pa = *(const bf16_8*)(Pw + lr*144 + hh*64 + g*16);
                #pragma unroll
                for (int dt = 0; dt < 4; ++dt)
                    o[dt] = __builtin_amdgcn_mfma_f32_16x16x32_bf16(
                        vf[dt][hh], pa, o[dt], 0, 0, 0);
            }
            __builtin_amdgcn_s_setprio(0);
        }

        ++kb; if (kb == 3) kb = 0;
    }

    // ---- epilogue: per-lane divide, LDS transpose, coalesced 128B row stores
    float linv = (l_run > 0.f) ? 1.f/l_run : 0.f;
    u16* ot = (u16*)Pw;                            // [d 64][q 16] stride 17
    #pragma unroll
    for (int dt = 0; dt < 4; ++dt)
        #pragma unroll
        for (int r = 0; r < 4; ++r)
            ot[(dt*16 + 4*g + r)*17 + lr] = f2bf(o[dt][r]*linv);
    asm volatile("s_waitcnt lgkmcnt(0)" ::: "memory");
    __builtin_amdgcn_sched_barrier(0);
    #pragma unroll
    for (int qq = 0; qq < 16; ++qq)
        AO[((size_t)(b*TT + qlo + qq))*D_MODEL + h*HDIM + lane] = ot[lane*17 + qq];
}

// ---------------------------------------------------------------- launch
extern "C" void kernel_launch(void* const* d_in, const int* in_sizes, int n_in,
                              void* d_out, int out_size, void* d_ws, size_t ws_size,
                              hipStream_t stream)
{
    const float* x  = (const float*)d_in[0];
    const unsigned char* mask = (const unsigned char*)d_in[1];
    const float* Wq = (const float*)d_in[2];
    const float* Wk = (const float*)d_in[3];
    const float* Wv = (const float*)d_in[4];
    const float* Wo = (const float*)d_in[5];
    float* out = (float*)d_out;

    char* ws = (char*)d_ws;
    u16* xb  = (u16*)(ws + 0);          // 8 MB (reused as AO after QKV)
    u16* wqb = (u16*)(ws + 8388608);
    u16* wkb = (u16*)(ws + 10485760);
    u16* wvb = (u16*)(ws + 12582912);
    u16* wob = (u16*)(ws + 14680064);
    u16* Qb  = (u16*)(ws + 16777216);
    u16* Kb  = (u16*)(ws + 25165824);
    u16* VTb = (u16*)(ws + 33554432);
    uint32_t* pmb = (uint32_t*)(ws + 41943040);   // 512 B mask bits
    u16* AOb = xb;

    cvtk<<<dim3(1024, 6), 256, 0, stream>>>(x, Wq, Wk, Wv, Wo, mask,
                                            xb, wqb, wkb, wvb, wob, pmb);
    gemm_qkv<<<dim3(256, 3), 256, 0, stream>>>(xb, wqb, wkb, wvb, Qb, Kb, VTb);
    attn_fwd<<<dim3(32, 16), 512, 0, stream>>>(Qb, Kb, VTb, pmb, AOb);
    gemm_out<<<dim3(256), 256, 0, stream>>>(AOb, wob, out);
}